// Round 1
// baseline (1813.688 us; speedup 1.0000x reference)
//
#include <hip/hip_runtime.h>
#include <hip/hip_bf16.h>

#define B_ 4
#define U_ 16
#define L_ 128
#define H_ 768
#define M_ 256
#define HID_ 150
#define NP_ 160   // HID padded to 160 so 16 k-groups of 10 cover it evenly

// ---------------------------------------------------------------------------
// Kernel 1: masked mean-pool over span positions.
// pooled[b,m,h] = (1/(en-st)) * sum_{l=st..en-1} hidden[b, utt, l, h]
// ---------------------------------------------------------------------------
__global__ __launch_bounds__(256) void pool_kernel(
    const float* __restrict__ hidden, const int* __restrict__ sutt,
    const int* __restrict__ sstart, const int* __restrict__ send,
    float* __restrict__ pooled)
{
    const int bm = blockIdx.x;           // 0..1023
    const int b  = bm >> 8;
    const int u  = sutt[bm];
    const int st = sstart[bm];
    const int en = send[bm];
    const float inv = 1.0f / (float)(en - st);
    const float* src = hidden + ((size_t)(b * U_ + u) * L_) * H_;
    for (int h = threadIdx.x; h < H_; h += 256) {
        float s = 0.0f;
        for (int l = st; l < en; ++l) s += src[(size_t)l * H_ + h];
        pooled[(size_t)bm * H_ + h] = s * inv;
    }
}

// ---------------------------------------------------------------------------
// Kernel 2: hi = pooled @ W1[:H], hj = pooled @ W1[H:2H]   (no bias here)
// One block per (b,m) row; W1a/W1b (921 KB) stay L2-resident.
// ---------------------------------------------------------------------------
__global__ __launch_bounds__(256) void hihj_kernel(
    const float* __restrict__ pooled, const float* __restrict__ W1,
    float* __restrict__ hi, float* __restrict__ hj)
{
    const int r = blockIdx.x;            // 0..1023
    __shared__ float srow[H_];
    for (int h = threadIdx.x; h < H_; h += 256)
        srow[h] = pooled[(size_t)r * H_ + h];
    __syncthreads();
    for (int c = threadIdx.x; c < 2 * HID_; c += 256) {
        const int k = (c < HID_) ? c : (c - HID_);
        const float* w = (c < HID_) ? (W1 + k) : (W1 + (size_t)H_ * HID_ + k);
        float s = 0.0f;
        #pragma unroll 4
        for (int h = 0; h < H_; ++h) s += srow[h] * w[(size_t)h * HID_];
        if (c < HID_) hi[(size_t)r * HID_ + k] = s;
        else          hj[(size_t)r * HID_ + k] = s;
    }
}

// ---------------------------------------------------------------------------
// Kernel 3: fused pair MLP.
// Tile = 16 i-rows x 4 j-cols = 64 pairs, lower-tri tiles only.
// Stage 1: h1 = relu(hi[i]+hj[j]+b1 + (pooled_i*pooled_j) @ W1c)  (K=768)
// Stage 2: h2 = relu(h1 @ W2 + b2)                                 (K=150)
// Stage 3: s  = h2 @ W3 + b3 -> logits[b,i,j]  (j<i only)
// Thread (a=tid>>4, tx=tid&15): 4 pairs (c=0..3) x 10 k (k0=tx*10).
// ---------------------------------------------------------------------------
__global__ __launch_bounds__(256) void pair_mlp_kernel(
    const float* __restrict__ pooled,
    const float* __restrict__ hi, const float* __restrict__ hj,
    const float* __restrict__ W1, const float* __restrict__ b1,
    const float* __restrict__ W2, const float* __restrict__ b2,
    const float* __restrict__ W3, const float* __restrict__ b3,
    float* __restrict__ logits)
{
    __shared__ float smem[14720];        // 57.5 KB, reused across stages
    const int b = blockIdx.y;
    int t = blockIdx.x;                  // 0..543 tile id
    int it = 0;
    while (2 * (it + 1) * (it + 2) <= t) ++it;
    const int jt = t - 2 * it * (it + 1);
    const int i0 = it * 16, j0 = jt * 4;
    const int tid = threadIdx.x;
    const int a  = tid >> 4;             // i-local 0..15
    const int tx = tid & 15;             // k-group
    const int k0 = tx * 10;
    const int bm = b * M_;

    float acc0[10], acc1[10], acc2[10], acc3[10];
    #pragma unroll
    for (int q = 0; q < 10; ++q) { acc0[q]=0; acc1[q]=0; acc2[q]=0; acc3[q]=0; }

    float* sPi = smem;            // [64 h][17 pad] i-rows   (1088)
    float* sPj = smem + 1088;     // [64 h][4]      j-rows   (256)
    float* sW  = smem + 1344;     // [64 h][160]    W1c pad  (10240)
    const float* W1c = W1 + (size_t)2 * H_ * HID_;

    // ---- stage 1: K=768 in chunks of 64 ----
    for (int h0 = 0; h0 < H_; h0 += 64) {
        for (int e = tid; e < 64 * NP_; e += 256) {
            int hh = e / NP_, k = e - hh * NP_;
            sW[e] = (k < HID_) ? W1c[(size_t)(h0 + hh) * HID_ + k] : 0.0f;
        }
        for (int e = tid; e < 16 * 64; e += 256) {
            int a2 = e >> 6, hh = e & 63;
            sPi[hh * 17 + a2] = pooled[(size_t)(bm + i0 + a2) * H_ + h0 + hh];
        }
        {
            int c = tid >> 6, hh = tid & 63;
            sPj[hh * 4 + c] = pooled[(size_t)(bm + j0 + c) * H_ + h0 + hh];
        }
        __syncthreads();
        #pragma unroll 4
        for (int hh = 0; hh < 64; ++hh) {
            float pi = sPi[hh * 17 + a];
            float4 pj = *(const float4*)&sPj[hh * 4];
            float p0 = pi * pj.x, p1 = pi * pj.y, p2 = pi * pj.z, p3 = pi * pj.w;
            const float* wr = &sW[hh * NP_ + k0];
            #pragma unroll
            for (int q2 = 0; q2 < 5; ++q2) {
                float2 w = *(const float2*)&wr[q2 * 2];
                acc0[q2*2]   += p0 * w.x;  acc0[q2*2+1] += p0 * w.y;
                acc1[q2*2]   += p1 * w.x;  acc1[q2*2+1] += p1 * w.y;
                acc2[q2*2]   += p2 * w.x;  acc2[q2*2+1] += p2 * w.y;
                acc3[q2*2]   += p3 * w.x;  acc3[q2*2+1] += p3 * w.y;
            }
        }
        __syncthreads();
    }

    // ---- h1 = relu(acc + hi + hj + b1) -> LDS [150][64] ----
    float* sH1 = smem;            // 150*64 = 9600
    float* sW2 = smem + 9600;     // 32*160 = 5120
    const int i = i0 + a;
    #pragma unroll
    for (int q = 0; q < 10; ++q) {
        int k = k0 + q;
        if (k < HID_) {
            float hiv = hi[(size_t)(bm + i) * HID_ + k] + b1[k];
            float v0 = fmaxf(acc0[q] + hiv + hj[(size_t)(bm + j0 + 0) * HID_ + k], 0.0f);
            float v1 = fmaxf(acc1[q] + hiv + hj[(size_t)(bm + j0 + 1) * HID_ + k], 0.0f);
            float v2 = fmaxf(acc2[q] + hiv + hj[(size_t)(bm + j0 + 2) * HID_ + k], 0.0f);
            float v3 = fmaxf(acc3[q] + hiv + hj[(size_t)(bm + j0 + 3) * HID_ + k], 0.0f);
            sH1[k * 64 + a * 4 + 0] = v0;
            sH1[k * 64 + a * 4 + 1] = v1;
            sH1[k * 64 + a * 4 + 2] = v2;
            sH1[k * 64 + a * 4 + 3] = v3;
        }
    }

    // ---- stage 2: h2 = relu(h1 @ W2 + b2), K=150 in chunks of 32 ----
    #pragma unroll
    for (int q = 0; q < 10; ++q) { acc0[q]=0; acc1[q]=0; acc2[q]=0; acc3[q]=0; }
    for (int kc = 0; kc < HID_; kc += 32) {
        const int len = (HID_ - kc < 32) ? (HID_ - kc) : 32;
        __syncthreads();   // sH1 visible (1st iter) / sW2 reads done (later iters)
        for (int e = tid; e < len * NP_; e += 256) {
            int kk = e / NP_, k2 = e - kk * NP_;
            sW2[e] = (k2 < HID_) ? W2[(size_t)(kc + kk) * HID_ + k2] : 0.0f;
        }
        __syncthreads();
        for (int kk = 0; kk < len; ++kk) {
            float4 h1v = *(const float4*)&sH1[(kc + kk) * 64 + a * 4];
            const float* wr = &sW2[kk * NP_ + k0];
            #pragma unroll
            for (int q2 = 0; q2 < 5; ++q2) {
                float2 w = *(const float2*)&wr[q2 * 2];
                acc0[q2*2]   += h1v.x * w.x;  acc0[q2*2+1] += h1v.x * w.y;
                acc1[q2*2]   += h1v.y * w.x;  acc1[q2*2+1] += h1v.y * w.y;
                acc2[q2*2]   += h1v.z * w.x;  acc2[q2*2+1] += h1v.z * w.y;
                acc3[q2*2]   += h1v.w * w.x;  acc3[q2*2+1] += h1v.w * w.y;
            }
        }
    }

    // ---- stage 3: s = relu(h2) @ W3 + b3 ----
    float part0 = 0, part1 = 0, part2 = 0, part3 = 0;
    #pragma unroll
    for (int q = 0; q < 10; ++q) {
        int k = k0 + q;
        if (k < HID_) {
            float b2v = b2[k], w3v = W3[k];
            part0 += fmaxf(acc0[q] + b2v, 0.0f) * w3v;
            part1 += fmaxf(acc1[q] + b2v, 0.0f) * w3v;
            part2 += fmaxf(acc2[q] + b2v, 0.0f) * w3v;
            part3 += fmaxf(acc3[q] + b2v, 0.0f) * w3v;
        }
    }
    #pragma unroll
    for (int off = 8; off >= 1; off >>= 1) {
        part0 += __shfl_down(part0, off, 16);
        part1 += __shfl_down(part1, off, 16);
        part2 += __shfl_down(part2, off, 16);
        part3 += __shfl_down(part3, off, 16);
    }
    if (tx == 0) {
        const float b3v = b3[0];
        const size_t base = (size_t)(bm + i) * M_;
        if (j0 + 0 < i) logits[base + j0 + 0] = part0 + b3v;
        if (j0 + 1 < i) logits[base + j0 + 1] = part1 + b3v;
        if (j0 + 2 < i) logits[base + j0 + 2] = part2 + b3v;
        if (j0 + 3 < i) logits[base + j0 + 3] = part3 + b3v;
    }
}

// ---------------------------------------------------------------------------
// Kernel 4: per-row softmax over j<=i, clipped label-mass NLL, atomic sum.
// probs for j>i are the reference's -1000 filler; clip(prob*label,eps,1-eps)
// makes every non-(valid & label=1) entry contribute exactly eps.
// ---------------------------------------------------------------------------
__global__ __launch_bounds__(256) void loss_kernel(
    const float* __restrict__ logits, const float* __restrict__ labels,
    float* __restrict__ out)
{
    const int bm = blockIdx.x;           // 0..1023 = b*256+i
    const int i  = bm & (M_ - 1);
    const int j  = threadIdx.x;          // 0..255
    __shared__ float red[4];
    __shared__ float bcast;

    float val = (j < i) ? logits[(size_t)bm * M_ + j]
                        : ((j == i) ? 0.0f : -1e30f);

    float m = val;
    #pragma unroll
    for (int off = 32; off >= 1; off >>= 1) m = fmaxf(m, __shfl_down(m, off, 64));
    const int wave = j >> 6, lane = j & 63;
    if (lane == 0) red[wave] = m;
    __syncthreads();
    if (j == 0) bcast = fmaxf(fmaxf(red[0], red[1]), fmaxf(red[2], red[3]));
    __syncthreads();
    const float mm = bcast;

    float e = (j <= i) ? expf(val - mm) : 0.0f;
    float s = e;
    #pragma unroll
    for (int off = 32; off >= 1; off >>= 1) s += __shfl_down(s, off, 64);
    __syncthreads();
    if (lane == 0) red[wave] = s;
    __syncthreads();
    if (j == 0) bcast = red[0] + red[1] + red[2] + red[3];
    __syncthreads();
    const float ssum = bcast;

    float prob = (j <= i) ? (e / ssum) : -1000.0f;
    float lab = labels[(size_t)bm * M_ + j];
    float tv = prob * lab;
    tv = fminf(fmaxf(tv, 1e-8f), 1.0f - 1e-8f);
    float rs = tv;
    #pragma unroll
    for (int off = 32; off >= 1; off >>= 1) rs += __shfl_down(rs, off, 64);
    __syncthreads();
    if (lane == 0) red[wave] = rs;
    __syncthreads();
    if (j == 0) atomicAdd(out, -logf(red[0] + red[1] + red[2] + red[3]));
}

// ---------------------------------------------------------------------------
extern "C" void kernel_launch(void* const* d_in, const int* in_sizes, int n_in,
                              void* d_out, int out_size, void* d_ws, size_t ws_size,
                              hipStream_t stream)
{
    const float* hidden = (const float*)d_in[0];
    const int*   sutt   = (const int*)d_in[1];
    const int*   sstart = (const int*)d_in[2];
    const int*   send   = (const int*)d_in[3];
    const float* labels = (const float*)d_in[4];
    const float* W1     = (const float*)d_in[5];
    const float* b1     = (const float*)d_in[6];
    const float* W2     = (const float*)d_in[7];
    const float* b2     = (const float*)d_in[8];
    const float* W3     = (const float*)d_in[9];
    const float* b3     = (const float*)d_in[10];

    float* ws     = (float*)d_ws;
    float* pooled = ws;                   // B*M*H      = 786432 floats
    float* hi     = ws + 786432;          // B*M*HID    = 153600
    float* hj     = ws + 940032;          // B*M*HID    = 153600
    float* logits = ws + 1093632;         // B*M*M      = 262144  (only j<i read)
    float* out    = (float*)d_out;

    hipMemsetAsync(d_out, 0, sizeof(float), stream);

    pool_kernel<<<dim3(B_ * M_), 256, 0, stream>>>(hidden, sutt, sstart, send, pooled);
    hihj_kernel<<<dim3(B_ * M_), 256, 0, stream>>>(pooled, W1, hi, hj);
    pair_mlp_kernel<<<dim3(544, B_), 256, 0, stream>>>(pooled, hi, hj,
                                                       W1, b1, W2, b2, W3, b3, logits);
    loss_kernel<<<dim3(B_ * M_), 256, 0, stream>>>(logits, labels, out);
}

// Round 2
// 381.365 us; speedup vs baseline: 4.7558x; 4.7558x over previous
//
#include <hip/hip_runtime.h>
#include <hip/hip_bf16.h>

#define B_ 4
#define U_ 16
#define L_ 128
#define H_ 768
#define M_ 256
#define HID_ 150

typedef _Float16 half8 __attribute__((ext_vector_type(8)));
typedef float floatx4 __attribute__((ext_vector_type(4)));

// ---------------------------------------------------------------------------
// Kernel 0: preconvert weights to f16, transposed+padded.
// W1cT [160][768]  (n-major; rows n>=150 zero)
// W2T  [160][160]  (n-major; rows n>=150 zero, cols k>=150 zero)
// ---------------------------------------------------------------------------
__global__ __launch_bounds__(256) void prep_kernel(
    const float* __restrict__ W1, const float* __restrict__ W2,
    _Float16* __restrict__ W1cT, _Float16* __restrict__ W2T)
{
    int idx = blockIdx.x * 256 + threadIdx.x;
    if (idx < 160 * 768) {
        int n = idx / 768, k = idx - n * 768;
        W1cT[idx] = (n < HID_) ? (_Float16)W1[(size_t)(2 * H_ + k) * HID_ + n]
                               : (_Float16)0.f;
        return;
    }
    idx -= 160 * 768;
    if (idx < 160 * 160) {
        int n = idx / 160, k = idx - n * 160;
        W2T[idx] = (n < HID_ && k < HID_) ? (_Float16)W2[(size_t)k * HID_ + n]
                                          : (_Float16)0.f;
    }
}

// ---------------------------------------------------------------------------
// Kernel 1: masked mean-pool; writes fp32 (for hihj) and f16 (for MFMA).
// ---------------------------------------------------------------------------
__global__ __launch_bounds__(256) void pool_kernel(
    const float* __restrict__ hidden, const int* __restrict__ sutt,
    const int* __restrict__ sstart, const int* __restrict__ send,
    float* __restrict__ pooled, _Float16* __restrict__ pooledh)
{
    const int bm = blockIdx.x;
    const int b  = bm >> 8;
    const int u  = sutt[bm];
    const int st = sstart[bm];
    const int en = send[bm];
    const float inv = 1.0f / (float)(en - st);
    const float* src = hidden + ((size_t)(b * U_ + u) * L_) * H_;
    for (int h = threadIdx.x; h < H_; h += 256) {
        float s = 0.0f;
        for (int l = st; l < en; ++l) s += src[(size_t)l * H_ + h];
        float v = s * inv;
        pooled[(size_t)bm * H_ + h]  = v;
        pooledh[(size_t)bm * H_ + h] = (_Float16)v;
    }
}

// ---------------------------------------------------------------------------
// Kernel 2: hi = pooled @ W1[:H], hj = pooled @ W1[H:2H]
// ---------------------------------------------------------------------------
__global__ __launch_bounds__(256) void hihj_kernel(
    const float* __restrict__ pooled, const float* __restrict__ W1,
    float* __restrict__ hi, float* __restrict__ hj)
{
    const int r = blockIdx.x;
    __shared__ float srow[H_];
    for (int h = threadIdx.x; h < H_; h += 256)
        srow[h] = pooled[(size_t)r * H_ + h];
    __syncthreads();
    for (int c = threadIdx.x; c < 2 * HID_; c += 256) {
        const int k = (c < HID_) ? c : (c - HID_);
        const float* w = (c < HID_) ? (W1 + k) : (W1 + (size_t)H_ * HID_ + k);
        float s = 0.0f;
        #pragma unroll 4
        for (int h = 0; h < H_; ++h) s += srow[h] * w[(size_t)h * HID_];
        if (c < HID_) hi[(size_t)r * HID_ + k] = s;
        else          hj[(size_t)r * HID_ + k] = s;
    }
}

// ---------------------------------------------------------------------------
// Kernel 3: fused pair MLP via MFMA f16 (fp32 accum).
// Block tile = 8 i x 16 j = 128 pairs; 4 waves, 2 m-tiles (16 pairs) each.
// m-tile = fixed i, 16 j's: A[m=j_local][k] = Pi[i,k]*Pj[j0+m,k].
// Stage 1: h1 = relu(prod@W1c + hi + hj + b1)  K=768
// Stage 2: h2pre = h1 @ W2                      K=160 (padded)
// Stage 3: s = relu(h2pre+b2) @ W3 + b3 -> logits (j<i)
// A-frag layout (16x16x32): lane holds A[m=lane&15][k=(lane>>4)*8+j]
// B-frag:                   lane holds B[k=(lane>>4)*8+j][n=lane&15]
// C/D:                      lane holds C[row=(lane>>4)*4+r][col=lane&15]
// ---------------------------------------------------------------------------
__global__ __launch_bounds__(256, 2) void pair_mlp_kernel(
    const _Float16* __restrict__ pooledh,
    const float* __restrict__ hi, const float* __restrict__ hj,
    const _Float16* __restrict__ W1cT, const float* __restrict__ b1,
    const _Float16* __restrict__ W2T, const float* __restrict__ b2,
    const float* __restrict__ W3, const float* __restrict__ b3,
    float* __restrict__ logits)
{
    // region A: Pi[8 rows]+Pj[16 rows], stride 776 f16 (pad +8 -> 2-way banks)
    // region B (reused): h1 [4 waves][32 pairs][168 f16]
    __shared__ __align__(16) _Float16 smem[21504];   // 43008 B -> 3 blocks/CU

    const int b = blockIdx.y;
    int t = blockIdx.x;                  // 0..271
    int it = 0;
    while (t >= (it >> 1) + 1) { t -= (it >> 1) + 1; ++it; }
    const int jt = t;
    const int i0 = it * 8, j0 = jt * 16;
    const int bm = b * M_;
    const int tid = threadIdx.x;
    const int wave = tid >> 6, lane = tid & 63;
    const int g = lane >> 4, l15 = lane & 15;
    const int t0 = wave * 2;

    // ---- stage Pi/Pj rows into LDS (16B chunks) ----
    for (int e = tid; e < 24 * 96; e += 256) {
        int r = e / 96, c = e - r * 96;
        int src = (r < 8) ? (bm + i0 + r) : (bm + j0 + (r - 8));
        *(float4*)&smem[r * 776 + c * 8] =
            *(const float4*)&pooledh[(size_t)src * H_ + c * 8];
    }
    __syncthreads();

    floatx4 acc[2][10];
    #pragma unroll
    for (int tt = 0; tt < 2; ++tt)
        #pragma unroll
        for (int u = 0; u < 10; ++u) acc[tt][u] = (floatx4){0.f, 0.f, 0.f, 0.f};

    const _Float16* pjB  = &smem[(8 + l15) * 776 + g * 8];
    const _Float16* pi0B = &smem[(t0 + 0) * 776 + g * 8];
    const _Float16* pi1B = &smem[(t0 + 1) * 776 + g * 8];
    const _Float16* wB   = W1cT + (size_t)l15 * H_ + g * 8;

    for (int kb = 0; kb < H_; kb += 32) {
        half8 pj = *(const half8*)(pjB + kb);
        half8 a0 = *(const half8*)(pi0B + kb) * pj;   // v_pk_mul_f16
        half8 a1 = *(const half8*)(pi1B + kb) * pj;
        #pragma unroll
        for (int u = 0; u < 10; ++u) {
            half8 bf = *(const half8*)(wB + (size_t)u * 16 * H_ + kb);
            acc[0][u] = __builtin_amdgcn_mfma_f32_16x16x32_f16(a0, bf, acc[0][u], 0, 0, 0);
            acc[1][u] = __builtin_amdgcn_mfma_f32_16x16x32_f16(a1, bf, acc[1][u], 0, 0, 0);
        }
    }
    __syncthreads();   // Pi/Pj dead -> region reused for h1

    // ---- epilogue 1: h1 -> LDS [wave][row=tt*16+j_local][ch 168pad] ----
    _Float16* h1w = &smem[wave * 32 * 168];
    #pragma unroll
    for (int tt = 0; tt < 2; ++tt) {
        const int i = i0 + t0 + tt;
        #pragma unroll
        for (int u = 0; u < 10; ++u) {
            const int n = u * 16 + l15;
            float hiv = 0.f;
            if (n < HID_) hiv = hi[(size_t)(bm + i) * HID_ + n] + b1[n];
            #pragma unroll
            for (int r = 0; r < 4; ++r) {
                const int jl = g * 4 + r;
                float v = 0.f;
                if (n < HID_) {
                    float hjv = hj[(size_t)(bm + j0 + jl) * HID_ + n];
                    v = fmaxf(acc[tt][u][r] + hiv + hjv, 0.f);
                }
                h1w[(tt * 16 + jl) * 168 + n] = (_Float16)v;
            }
        }
    }
    __syncthreads();

    // ---- stage 2: h1 @ W2, K=160 ----
    floatx4 acc2[2][10];
    #pragma unroll
    for (int tt = 0; tt < 2; ++tt)
        #pragma unroll
        for (int u = 0; u < 10; ++u) acc2[tt][u] = (floatx4){0.f, 0.f, 0.f, 0.f};

    const _Float16* a2B0 = &h1w[(0 * 16 + l15) * 168 + g * 8];
    const _Float16* a2B1 = &h1w[(1 * 16 + l15) * 168 + g * 8];
    const _Float16* w2B  = W2T + (size_t)l15 * 160 + g * 8;
    #pragma unroll
    for (int kb = 0; kb < 160; kb += 32) {
        half8 a0 = *(const half8*)(a2B0 + kb);
        half8 a1 = *(const half8*)(a2B1 + kb);
        #pragma unroll
        for (int u = 0; u < 10; ++u) {
            half8 bf = *(const half8*)(w2B + u * 16 * 160 + kb);
            acc2[0][u] = __builtin_amdgcn_mfma_f32_16x16x32_f16(a0, bf, acc2[0][u], 0, 0, 0);
            acc2[1][u] = __builtin_amdgcn_mfma_f32_16x16x32_f16(a1, bf, acc2[1][u], 0, 0, 0);
        }
    }

    // ---- stage 3: s = relu(h2pre + b2) @ W3 + b3 ----
    #pragma unroll
    for (int tt = 0; tt < 2; ++tt) {
        float part[4] = {0.f, 0.f, 0.f, 0.f};
        #pragma unroll
        for (int u = 0; u < 10; ++u) {
            const int n = u * 16 + l15;
            float b2v = 0.f, w3v = 0.f;
            if (n < HID_) { b2v = b2[n]; w3v = W3[n]; }
            #pragma unroll
            for (int r = 0; r < 4; ++r)
                part[r] += fmaxf(acc2[tt][u][r] + b2v, 0.f) * w3v;
        }
        #pragma unroll
        for (int r = 0; r < 4; ++r) {
            float p = part[r];
            p += __shfl_down(p, 8, 16);
            p += __shfl_down(p, 4, 16);
            p += __shfl_down(p, 2, 16);
            p += __shfl_down(p, 1, 16);
            if (l15 == 0) {
                const int i = i0 + t0 + tt;
                const int j = j0 + g * 4 + r;
                if (j < i) logits[(size_t)(bm + i) * M_ + j] = p + b3[0];
            }
        }
    }
}

// ---------------------------------------------------------------------------
// Kernel 4: per-row softmax over j<=i, clipped label-mass NLL, atomic sum.
// ---------------------------------------------------------------------------
__global__ __launch_bounds__(256) void loss_kernel(
    const float* __restrict__ logits, const float* __restrict__ labels,
    float* __restrict__ out)
{
    const int bm = blockIdx.x;
    const int i  = bm & (M_ - 1);
    const int j  = threadIdx.x;
    __shared__ float red[4];
    __shared__ float bcast;

    float val = (j < i) ? logits[(size_t)bm * M_ + j]
                        : ((j == i) ? 0.0f : -1e30f);

    float m = val;
    #pragma unroll
    for (int off = 32; off >= 1; off >>= 1) m = fmaxf(m, __shfl_down(m, off, 64));
    const int wave = j >> 6, lane = j & 63;
    if (lane == 0) red[wave] = m;
    __syncthreads();
    if (j == 0) bcast = fmaxf(fmaxf(red[0], red[1]), fmaxf(red[2], red[3]));
    __syncthreads();
    const float mm = bcast;

    float e = (j <= i) ? expf(val - mm) : 0.0f;
    float s = e;
    #pragma unroll
    for (int off = 32; off >= 1; off >>= 1) s += __shfl_down(s, off, 64);
    __syncthreads();
    if (lane == 0) red[wave] = s;
    __syncthreads();
    if (j == 0) bcast = red[0] + red[1] + red[2] + red[3];
    __syncthreads();
    const float ssum = bcast;

    float prob = (j <= i) ? (e / ssum) : -1000.0f;
    float lab = labels[(size_t)bm * M_ + j];
    float tv = prob * lab;
    tv = fminf(fmaxf(tv, 1e-8f), 1.0f - 1e-8f);
    float rs = tv;
    #pragma unroll
    for (int off = 32; off >= 1; off >>= 1) rs += __shfl_down(rs, off, 64);
    __syncthreads();
    if (lane == 0) red[wave] = rs;
    __syncthreads();
    if (j == 0) atomicAdd(out, -logf(red[0] + red[1] + red[2] + red[3]));
}

// ---------------------------------------------------------------------------
extern "C" void kernel_launch(void* const* d_in, const int* in_sizes, int n_in,
                              void* d_out, int out_size, void* d_ws, size_t ws_size,
                              hipStream_t stream)
{
    const float* hidden = (const float*)d_in[0];
    const int*   sutt   = (const int*)d_in[1];
    const int*   sstart = (const int*)d_in[2];
    const int*   send   = (const int*)d_in[3];
    const float* labels = (const float*)d_in[4];
    const float* W1     = (const float*)d_in[5];
    const float* b1     = (const float*)d_in[6];
    const float* W2     = (const float*)d_in[7];
    const float* b2     = (const float*)d_in[8];
    const float* W3     = (const float*)d_in[9];
    const float* b3     = (const float*)d_in[10];

    float* ws      = (float*)d_ws;
    float* pooled  = ws;                       // 786432 f32
    float* hi      = ws + 786432;              // 153600 f32
    float* hj      = ws + 940032;              // 153600 f32
    float* logits  = ws + 1093632;             // 262144 f32
    _Float16* pooledh = (_Float16*)(ws + 1355776); // 786432 f16
    _Float16* W1cT    = (_Float16*)(ws + 1748992); // 160*768 f16
    _Float16* W2T     = (_Float16*)(ws + 1810432); // 160*160 f16
    float* out = (float*)d_out;

    hipMemsetAsync(d_out, 0, sizeof(float), stream);

    prep_kernel<<<dim3(580), 256, 0, stream>>>(W1, W2, W1cT, W2T);
    pool_kernel<<<dim3(B_ * M_), 256, 0, stream>>>(hidden, sutt, sstart, send,
                                                   pooled, pooledh);
    hihj_kernel<<<dim3(B_ * M_), 256, 0, stream>>>(pooled, W1, hi, hj);
    pair_mlp_kernel<<<dim3(272, B_), 256, 0, stream>>>(pooledh, hi, hj,
                                                       W1cT, b1, W2T, b2, W3, b3,
                                                       logits);
    loss_kernel<<<dim3(B_ * M_), 256, 0, stream>>>(logits, labels, out);
}

// Round 3
// 228.525 us; speedup vs baseline: 7.9365x; 1.6688x over previous
//
#include <hip/hip_runtime.h>
#include <hip/hip_bf16.h>

#define B_ 4
#define U_ 16
#define L_ 128
#define H_ 768
#define M_ 256
#define HID_ 150

typedef _Float16 half8 __attribute__((ext_vector_type(8)));
typedef float floatx4 __attribute__((ext_vector_type(4)));

// ---------------------------------------------------------------------------
// Kernel 0: prepack weights to f16 in MFMA-fragment-contiguous layouts.
// W1s: 24 k-chunks x 10 n-tiles x 64 lanes x 8 f16. Lane l of tile u holds
//      B[k = kc*32+(l>>4)*8+j][n = u*16+(l&15)]  -> ds_read at lane*16B.
// W2s: same, 5 k-chunks (K padded 160, zeros beyond 150).
// W1abT: [320][768] n-major; rows 0..149 = W1a cols, 160..309 = W1b cols.
// ---------------------------------------------------------------------------
__global__ __launch_bounds__(256) void prep_kernel(
    const float* __restrict__ W1, const float* __restrict__ W2,
    _Float16* __restrict__ W1s, _Float16* __restrict__ W2s,
    _Float16* __restrict__ W1abT)
{
    int idx = blockIdx.x * 256 + threadIdx.x;
    if (idx < 122880) {   // W1s
        int j = idx & 7, l = (idx >> 3) & 63;
        int u = (idx >> 9) % 10, kc = idx / 5120;
        int n = u * 16 + (l & 15);
        int k = kc * 32 + (l >> 4) * 8 + j;
        W1s[idx] = (n < HID_) ? (_Float16)W1[(size_t)(2 * H_ + k) * HID_ + n]
                              : (_Float16)0.f;
        return;
    }
    idx -= 122880;
    if (idx < 25600) {    // W2s
        int j = idx & 7, l = (idx >> 3) & 63;
        int u = (idx >> 9) % 10, kc = idx / 5120;
        int n = u * 16 + (l & 15);
        int k = kc * 32 + (l >> 4) * 8 + j;
        W2s[idx] = (n < HID_ && k < HID_) ? (_Float16)W2[(size_t)k * HID_ + n]
                                          : (_Float16)0.f;
        return;
    }
    idx -= 25600;
    if (idx < 245760) {   // W1abT
        int n = idx / H_, k = idx - n * H_;
        float v = 0.f;
        if (n < 160) { if (n < HID_) v = W1[(size_t)k * HID_ + n]; }
        else { int c = n - 160; if (c < HID_) v = W1[(size_t)(H_ + k) * HID_ + c]; }
        W1abT[idx] = (_Float16)v;
    }
}

// ---------------------------------------------------------------------------
// Kernel 1: masked mean-pool -> f16.
// ---------------------------------------------------------------------------
__global__ __launch_bounds__(256) void pool_kernel(
    const float* __restrict__ hidden, const int* __restrict__ sutt,
    const int* __restrict__ sstart, const int* __restrict__ send,
    _Float16* __restrict__ pooledh)
{
    const int bm = blockIdx.x;
    const int b  = bm >> 8;
    const int u  = sutt[bm];
    const int st = sstart[bm];
    const int en = send[bm];
    const float inv = 1.0f / (float)(en - st);
    const float* src = hidden + ((size_t)(b * U_ + u) * L_) * H_;
    for (int h = threadIdx.x; h < H_; h += 256) {
        float s = 0.0f;
        for (int l = st; l < en; ++l) s += src[(size_t)l * H_ + h];
        pooledh[(size_t)bm * H_ + h] = (_Float16)(s * inv);
    }
}

// ---------------------------------------------------------------------------
// Kernel 2: hi/hj = pooled @ W1a / W1b via MFMA. 64 blocks x 16 rows.
// Waves split the 20 n-tiles (5 each). B-frags straight from L2.
// ---------------------------------------------------------------------------
__global__ __launch_bounds__(256) void hihj_kernel(
    const _Float16* __restrict__ pooledh, const _Float16* __restrict__ W1abT,
    float* __restrict__ hi, float* __restrict__ hj)
{
    const int blk = blockIdx.x;          // rows blk*16 .. +15
    const int tid = threadIdx.x;
    const int w = tid >> 6, lane = tid & 63;
    const int g = lane >> 4, l15 = lane & 15;
    floatx4 acc[5];
    #pragma unroll
    for (int u = 0; u < 5; ++u) acc[u] = (floatx4){0.f, 0.f, 0.f, 0.f};
    const _Float16* aB = pooledh + (size_t)(blk * 16 + l15) * H_ + g * 8;
    const _Float16* bB = W1abT + (size_t)(w * 5 * 16 + l15) * H_ + g * 8;
    #pragma unroll 2
    for (int kb = 0; kb < H_; kb += 32) {
        half8 av = *(const half8*)(aB + kb);
        #pragma unroll
        for (int u = 0; u < 5; ++u) {
            half8 bv = *(const half8*)(bB + (size_t)u * 16 * H_ + kb);
            acc[u] = __builtin_amdgcn_mfma_f32_16x16x32_f16(av, bv, acc[u], 0, 0, 0);
        }
    }
    const int row = blk * 16 + g * 4;
    #pragma unroll
    for (int u = 0; u < 5; ++u) {
        int n = (w * 5 + u) * 16 + l15;
        #pragma unroll
        for (int r = 0; r < 4; ++r) {
            float v = acc[u][r];
            int rr = row + r;
            if (n < HID_) hi[(size_t)rr * HID_ + n] = v;
            else if (n >= 160 && n < 160 + HID_) hj[(size_t)rr * HID_ + (n - 160)] = v;
        }
    }
}

// ---------------------------------------------------------------------------
// Kernel 3: fused pair MLP. Block = 128 thr (2 waves), tile 8i x 16j.
// Wave w owns i-rows w*4..w*4+3 (4 m-tiles x 10 n-tiles, acc 160 VGPR).
// B: LDS double-buffered 1KB-contiguous fragments from W1s/W2s.
// A: built per chunk from global pooledh gathers (pj) + broadcasts (pi).
// ---------------------------------------------------------------------------
__global__ __launch_bounds__(128, 1) void pair_mlp_kernel(
    const _Float16* __restrict__ pooledh,
    const float* __restrict__ hi, const float* __restrict__ hj,
    const _Float16* __restrict__ W1s, const float* __restrict__ b1,
    const _Float16* __restrict__ W2s, const float* __restrict__ b2,
    const float* __restrict__ W3, const float* __restrict__ b3,
    float* __restrict__ logits)
{
    // [0,10240): B double buffer (2 x 5120 f16). [10240,30720): h1 [128][160]
    __shared__ __align__(16) _Float16 smem[30720];

    const int b = blockIdx.y;
    int t = blockIdx.x;                  // 0..271
    int it = 0;
    while (t >= (it >> 1) + 1) { t -= (it >> 1) + 1; ++it; }
    const int i0 = it * 8, j0 = t * 16;
    const int bm = b * M_;
    const int tid = threadIdx.x;
    const int w = tid >> 6, lane = tid & 63;
    const int g = lane >> 4, l15 = lane & 15;

    const _Float16* pjp = pooledh + (size_t)(bm + j0 + l15) * H_ + g * 8;
    const _Float16* pip = pooledh + (size_t)(bm + i0 + w * 4) * H_ + g * 8;

    floatx4 acc[4][10];
    #pragma unroll
    for (int a = 0; a < 4; ++a)
        #pragma unroll
        for (int u = 0; u < 10; ++u) acc[a][u] = (floatx4){0.f, 0.f, 0.f, 0.f};

    // ---- prologue: A(0) + stage B-chunk 0 into buf0 ----
    half8 pjc = *(const half8*)pjp;
    half8 pic[4];
    #pragma unroll
    for (int a = 0; a < 4; ++a) pic[a] = *(const half8*)(pip + (size_t)a * H_);
    {
        half8 st[5];
        #pragma unroll
        for (int q = 0; q < 5; ++q)
            st[q] = *(const half8*)(W1s + (size_t)(tid + q * 128) * 8);
        #pragma unroll
        for (int q = 0; q < 5; ++q)
            *(half8*)&smem[(tid + q * 128) * 8] = st[q];
    }
    __syncthreads();

    // ---- stage 1 K-loop: 24 chunks of 32 ----
    for (int kc = 0; kc < 24; ++kc) {
        const int p = kc & 1;
        half8 pjn, pin[4], stn[5];
        if (kc < 23) {
            const int kb = (kc + 1) * 32;
            pjn = *(const half8*)(pjp + kb);
            #pragma unroll
            for (int a = 0; a < 4; ++a)
                pin[a] = *(const half8*)(pip + (size_t)a * H_ + kb);
            const _Float16* src = W1s + (size_t)(kc + 1) * 5120;
            #pragma unroll
            for (int q = 0; q < 5; ++q)
                stn[q] = *(const half8*)(src + (size_t)(tid + q * 128) * 8);
        }
        half8 af[4];
        #pragma unroll
        for (int a = 0; a < 4; ++a) af[a] = pic[a] * pjc;
        const _Float16* bufc = &smem[p * 5120];
        #pragma unroll
        for (int u = 0; u < 10; ++u) {
            half8 bf = *(const half8*)&bufc[u * 512 + lane * 8];
            acc[0][u] = __builtin_amdgcn_mfma_f32_16x16x32_f16(af[0], bf, acc[0][u], 0, 0, 0);
            acc[1][u] = __builtin_amdgcn_mfma_f32_16x16x32_f16(af[1], bf, acc[1][u], 0, 0, 0);
            acc[2][u] = __builtin_amdgcn_mfma_f32_16x16x32_f16(af[2], bf, acc[2][u], 0, 0, 0);
            acc[3][u] = __builtin_amdgcn_mfma_f32_16x16x32_f16(af[3], bf, acc[3][u], 0, 0, 0);
        }
        if (kc < 23) {
            _Float16* dst = &smem[(1 - p) * 5120];
            #pragma unroll
            for (int q = 0; q < 5; ++q)
                *(half8*)&dst[(tid + q * 128) * 8] = stn[q];
            pjc = pjn;
            #pragma unroll
            for (int a = 0; a < 4; ++a) pic[a] = pin[a];
        }
        __syncthreads();
    }

    // ---- epilogue 1: h1 = relu(acc + hi + hj + b1) -> LDS [128][160] f16 ----
    _Float16* h1 = &smem[10240];
    #pragma unroll
    for (int u = 0; u < 10; ++u) {
        const int n = u * 16 + l15;
        const bool ok = (n < HID_);
        float hbv[4], hjv[4];
        float b1v = ok ? b1[n] : 0.f;
        #pragma unroll
        for (int a = 0; a < 4; ++a)
            hbv[a] = ok ? hi[(size_t)(bm + i0 + w * 4 + a) * HID_ + n] + b1v : 0.f;
        #pragma unroll
        for (int r = 0; r < 4; ++r)
            hjv[r] = ok ? hj[(size_t)(bm + j0 + g * 4 + r) * HID_ + n] : 0.f;
        #pragma unroll
        for (int a = 0; a < 4; ++a)
            #pragma unroll
            for (int r = 0; r < 4; ++r) {
                float v = ok ? fmaxf(acc[a][u][r] + hbv[a] + hjv[r], 0.f) : 0.f;
                h1[((w * 4 + a) * 16 + g * 4 + r) * 160 + n] = (_Float16)v;
            }
    }
    // stage W2s chunk 0 -> buf0
    {
        half8 st[5];
        #pragma unroll
        for (int q = 0; q < 5; ++q)
            st[q] = *(const half8*)(W2s + (size_t)(tid + q * 128) * 8);
        #pragma unroll
        for (int q = 0; q < 5; ++q)
            *(half8*)&smem[(tid + q * 128) * 8] = st[q];
    }
    __syncthreads();

    // ---- stage 2: h2pre = h1 @ W2, K=160 in 5 chunks ----
    floatx4 acc2[4][10];
    #pragma unroll
    for (int a = 0; a < 4; ++a)
        #pragma unroll
        for (int u = 0; u < 10; ++u) acc2[a][u] = (floatx4){0.f, 0.f, 0.f, 0.f};

    for (int kc = 0; kc < 5; ++kc) {
        const int p = kc & 1;
        half8 stn[5];
        if (kc < 4) {
            const _Float16* src = W2s + (size_t)(kc + 1) * 5120;
            #pragma unroll
            for (int q = 0; q < 5; ++q)
                stn[q] = *(const half8*)(src + (size_t)(tid + q * 128) * 8);
        }
        half8 a2[4];
        #pragma unroll
        for (int a = 0; a < 4; ++a)
            a2[a] = *(const half8*)&h1[((w * 4 + a) * 16 + l15) * 160 + kc * 32 + g * 8];
        const _Float16* bufc = &smem[p * 5120];
        #pragma unroll
        for (int u = 0; u < 10; ++u) {
            half8 bf = *(const half8*)&bufc[u * 512 + lane * 8];
            acc2[0][u] = __builtin_amdgcn_mfma_f32_16x16x32_f16(a2[0], bf, acc2[0][u], 0, 0, 0);
            acc2[1][u] = __builtin_amdgcn_mfma_f32_16x16x32_f16(a2[1], bf, acc2[1][u], 0, 0, 0);
            acc2[2][u] = __builtin_amdgcn_mfma_f32_16x16x32_f16(a2[2], bf, acc2[2][u], 0, 0, 0);
            acc2[3][u] = __builtin_amdgcn_mfma_f32_16x16x32_f16(a2[3], bf, acc2[3][u], 0, 0, 0);
        }
        if (kc < 4) {
            _Float16* dst = &smem[(1 - p) * 5120];
            #pragma unroll
            for (int q = 0; q < 5; ++q)
                *(half8*)&dst[(tid + q * 128) * 8] = stn[q];
        }
        __syncthreads();
    }

    // ---- stage 3: s = relu(h2pre + b2) @ W3 + b3 -> logits ----
    float part[4][4];
    #pragma unroll
    for (int a = 0; a < 4; ++a)
        #pragma unroll
        for (int r = 0; r < 4; ++r) part[a][r] = 0.f;
    #pragma unroll
    for (int u = 0; u < 10; ++u) {
        const int n = u * 16 + l15;
        float b2v = 0.f, w3v = 0.f;
        if (n < HID_) { b2v = b2[n]; w3v = W3[n]; }
        #pragma unroll
        for (int a = 0; a < 4; ++a)
            #pragma unroll
            for (int r = 0; r < 4; ++r)
                part[a][r] += fmaxf(acc2[a][u][r] + b2v, 0.f) * w3v;
    }
    const float b3v = b3[0];
    #pragma unroll
    for (int a = 0; a < 4; ++a)
        #pragma unroll
        for (int r = 0; r < 4; ++r) {
            float p = part[a][r];
            p += __shfl_down(p, 8, 16);
            p += __shfl_down(p, 4, 16);
            p += __shfl_down(p, 2, 16);
            p += __shfl_down(p, 1, 16);
            if (l15 == 0) {
                const int i = i0 + w * 4 + a;
                const int j = j0 + g * 4 + r;
                if (j < i) logits[(size_t)(bm + i) * M_ + j] = p + b3v;
            }
        }
}

// ---------------------------------------------------------------------------
// Kernel 4: per-row softmax over j<=i, clipped label-mass NLL, atomic sum.
// ---------------------------------------------------------------------------
__global__ __launch_bounds__(256) void loss_kernel(
    const float* __restrict__ logits, const float* __restrict__ labels,
    float* __restrict__ out)
{
    const int bm = blockIdx.x;
    const int i  = bm & (M_ - 1);
    const int j  = threadIdx.x;
    __shared__ float red[4];
    __shared__ float bcast;

    float val = (j < i) ? logits[(size_t)bm * M_ + j]
                        : ((j == i) ? 0.0f : -1e30f);

    float m = val;
    #pragma unroll
    for (int off = 32; off >= 1; off >>= 1) m = fmaxf(m, __shfl_down(m, off, 64));
    const int wave = j >> 6, lane = j & 63;
    if (lane == 0) red[wave] = m;
    __syncthreads();
    if (j == 0) bcast = fmaxf(fmaxf(red[0], red[1]), fmaxf(red[2], red[3]));
    __syncthreads();
    const float mm = bcast;

    float e = (j <= i) ? expf(val - mm) : 0.0f;
    float s = e;
    #pragma unroll
    for (int off = 32; off >= 1; off >>= 1) s += __shfl_down(s, off, 64);
    __syncthreads();
    if (lane == 0) red[wave] = s;
    __syncthreads();
    if (j == 0) bcast = red[0] + red[1] + red[2] + red[3];
    __syncthreads();
    const float ssum = bcast;

    float prob = (j <= i) ? (e / ssum) : -1000.0f;
    float lab = labels[(size_t)bm * M_ + j];
    float tv = prob * lab;
    tv = fminf(fmaxf(tv, 1e-8f), 1.0f - 1e-8f);
    float rs = tv;
    #pragma unroll
    for (int off = 32; off >= 1; off >>= 1) rs += __shfl_down(rs, off, 64);
    __syncthreads();
    if (lane == 0) red[wave] = rs;
    __syncthreads();
    if (j == 0) atomicAdd(out, -logf(red[0] + red[1] + red[2] + red[3]));
}

// ---------------------------------------------------------------------------
extern "C" void kernel_launch(void* const* d_in, const int* in_sizes, int n_in,
                              void* d_out, int out_size, void* d_ws, size_t ws_size,
                              hipStream_t stream)
{
    const float* hidden = (const float*)d_in[0];
    const int*   sutt   = (const int*)d_in[1];
    const int*   sstart = (const int*)d_in[2];
    const int*   send   = (const int*)d_in[3];
    const float* labels = (const float*)d_in[4];
    const float* W1     = (const float*)d_in[5];
    const float* b1     = (const float*)d_in[6];
    const float* W2     = (const float*)d_in[7];
    const float* b2     = (const float*)d_in[8];
    const float* W3     = (const float*)d_in[9];
    const float* b3     = (const float*)d_in[10];

    float* ws = (float*)d_ws;
    float* hi      = ws;                        // 153600 f32
    float* hj      = ws + 153600;               // 153600 f32
    float* logits  = ws + 307200;               // 262144 f32
    _Float16* pooledh = (_Float16*)(ws + 569344);  // 786432 f16
    _Float16* W1s     = (_Float16*)(ws + 962560);  // 122880 f16
    _Float16* W2s     = (_Float16*)(ws + 1024000); // 25600 f16
    _Float16* W1abT   = (_Float16*)(ws + 1036800); // 245760 f16
    float* out = (float*)d_out;

    hipMemsetAsync(d_out, 0, sizeof(float), stream);

    prep_kernel<<<dim3(1540), 256, 0, stream>>>(W1, W2, W1s, W2s, W1abT);
    pool_kernel<<<dim3(B_ * M_), 256, 0, stream>>>(hidden, sutt, sstart, send, pooledh);
    hihj_kernel<<<dim3(64), 256, 0, stream>>>(pooledh, W1abT, hi, hj);
    pair_mlp_kernel<<<dim3(272, B_), 128, 0, stream>>>(pooledh, hi, hj,
                                                       W1s, b1, W2s, b2, W3, b3,
                                                       logits);
    loss_kernel<<<dim3(B_ * M_), 256, 0, stream>>>(logits, labels, out);
}